// Round 4
// baseline (2418.934 us; speedup 1.0000x reference)
//
#include <hip/hip_runtime.h>
#include <hip/hip_bf16.h>
#include <math.h>

// RWKV-7 TimeMix. R4: col-per-lane wkv7 (9-reg ring slots) + bf16-MFMA big GEMMs.
// B=4 T=2048 C=768 H=12 N=64, LAYER_ID=1.

#define B_  4
#define T_  2048
#define C_  768
#define H_  12

typedef __attribute__((ext_vector_type(8))) short bf16x8;
typedef __attribute__((ext_vector_type(4))) float f32x4;

#define GLD16(gsrc, ldst)                                                     \
  __builtin_amdgcn_global_load_lds(                                           \
      (const __attribute__((address_space(1))) void*)(gsrc),                  \
      (__attribute__((address_space(3))) void*)(ldst), 16, 0, 0)

static __device__ __forceinline__ float wave_sum64(float v) {
#pragma unroll
  for (int m = 32; m > 0; m >>= 1) v += __shfl_xor(v, m);
  return v;
}

static __device__ __forceinline__ short bf16b(float f) {
  __hip_bfloat16 h = __float2bfloat16(f);
  return *reinterpret_cast<short*>(&h);
}

// ---------------- bf16 MFMA GEMM ----------------
// C[M,N] = A[M,K](bf16) @ Bw[N,K](bf16)^T, fp32 out. 128x128 tile, BK=32.
__global__ __launch_bounds__(256) void gemm_bf16_k(
    const short* __restrict__ A, const short* __restrict__ Bw,
    float* __restrict__ C, int M, int N, int K) {
  __shared__ short As[128 * 32];
  __shared__ short Bs[128 * 32];
  const int tid = threadIdx.x;
  const int wave = tid >> 6, lane = tid & 63;
  const int m0 = blockIdx.y * 128, n0 = blockIdx.x * 128;
  const int wm = (wave >> 1) * 64, wn = (wave & 1) * 64;
  const int fr = lane & 15, fk = (lane >> 4) * 8;

  f32x4 acc[4][4];
#pragma unroll
  for (int i = 0; i < 4; i++)
#pragma unroll
    for (int j = 0; j < 4; j++) acc[i][j] = (f32x4){0.f, 0.f, 0.f, 0.f};

  const int srow = tid >> 2, scol = (tid & 3) * 8;
  const short* gA = A + (size_t)(m0 + srow) * K + scol;
  const short* gB = Bw + (size_t)(n0 + srow) * K + scol;
  short* lA0 = &As[wave * 512];
  short* lA1 = &As[2048 + wave * 512];
  short* lB0 = &Bs[wave * 512];
  short* lB1 = &Bs[2048 + wave * 512];

  for (int k0 = 0; k0 < K; k0 += 32) {
    GLD16(gA + k0, lA0);
    GLD16(gA + (size_t)64 * K + k0, lA1);
    GLD16(gB + k0, lB0);
    GLD16(gB + (size_t)64 * K + k0, lB1);
    __syncthreads();

    bf16x8 af[4], bf[4];
#pragma unroll
    for (int i = 0; i < 4; i++)
      af[i] = *(const bf16x8*)&As[(wm + i * 16 + fr) * 32 + fk];
#pragma unroll
    for (int j = 0; j < 4; j++)
      bf[j] = *(const bf16x8*)&Bs[(wn + j * 16 + fr) * 32 + fk];
#pragma unroll
    for (int i = 0; i < 4; i++)
#pragma unroll
      for (int j = 0; j < 4; j++)
        acc[i][j] =
            __builtin_amdgcn_mfma_f32_16x16x32_bf16(af[i], bf[j], acc[i][j], 0, 0, 0);
    __syncthreads();
  }

#pragma unroll
  for (int i = 0; i < 4; i++) {
    const int gm = m0 + wm + i * 16 + (lane >> 4) * 4;
#pragma unroll
    for (int j = 0; j < 4; j++) {
      const int gn = n0 + wn + j * 16 + fr;
#pragma unroll
      for (int rix = 0; rix < 4; rix++)
        C[(size_t)(gm + rix) * N + gn] = acc[i][j][rix];
    }
  }
}

// ---------------- fp32 GEMM (small paths) ----------------
enum { EPI_NONE = 0, EPI_TANH, EPI_WDECAY, EPI_SIGBIAS, EPI_SIGMOID, EPI_VMIX };

template <bool MIX, bool BT, int EPI>
__global__ __launch_bounds__(256) void gemm_k(
    const float* __restrict__ A, const float* __restrict__ Bm,
    float* __restrict__ Cc, int M, int N, int K,
    const float* __restrict__ lam, const float* __restrict__ bias,
    const float* __restrict__ ex1, const float* __restrict__ ex2) {
  __shared__ float As[64][20];
  __shared__ float Bs[64][20];
  const int tid = threadIdx.x;
  const int n0 = blockIdx.x * 64;
  const int m0 = blockIdx.y * 64;
  const int tx = tid & 15, ty = tid >> 4;

  float acc[4][4];
#pragma unroll
  for (int i = 0; i < 4; i++)
#pragma unroll
    for (int j = 0; j < 4; j++) acc[i][j] = 0.f;

  const int lm = tid >> 2;
  const int lk4 = (tid & 3) * 4;

  for (int k0 = 0; k0 < K; k0 += 16) {
    {
      const int gm = m0 + lm;
      const float* ap = A + (size_t)gm * K + k0 + lk4;
      float4 xa = *(const float4*)ap;
      if (MIX) {
        float4 xp = make_float4(0.f, 0.f, 0.f, 0.f);
        if ((gm % T_) != 0) xp = *(const float4*)(ap - K);
        const float4 l4 = *(const float4*)(lam + k0 + lk4);
        xa.x += (xp.x - xa.x) * l4.x;
        xa.y += (xp.y - xa.y) * l4.y;
        xa.z += (xp.z - xa.z) * l4.z;
        xa.w += (xp.w - xa.w) * l4.w;
      }
      *(float4*)&As[lm][lk4] = xa;
    }
    if (BT) {
      const int gn = n0 + lm;
      const float4 bv = *(const float4*)(Bm + (size_t)gn * K + k0 + lk4);
      *(float4*)&Bs[lm][lk4] = bv;
    } else {
      const int kl = tid >> 4;
      const int nl = (tid & 15) * 4;
      const float4 bv = *(const float4*)(Bm + (size_t)(k0 + kl) * N + n0 + nl);
      Bs[nl + 0][kl] = bv.x;
      Bs[nl + 1][kl] = bv.y;
      Bs[nl + 2][kl] = bv.z;
      Bs[nl + 3][kl] = bv.w;
    }
    __syncthreads();

#pragma unroll
    for (int kb = 0; kb < 16; kb += 4) {
      float a4[4][4], b4[4][4];
#pragma unroll
      for (int i = 0; i < 4; i++) {
        const float4 t = *(const float4*)&As[ty * 4 + i][kb];
        a4[i][0] = t.x; a4[i][1] = t.y; a4[i][2] = t.z; a4[i][3] = t.w;
      }
#pragma unroll
      for (int j = 0; j < 4; j++) {
        const float4 t = *(const float4*)&Bs[tx * 4 + j][kb];
        b4[j][0] = t.x; b4[j][1] = t.y; b4[j][2] = t.z; b4[j][3] = t.w;
      }
#pragma unroll
      for (int u = 0; u < 4; u++)
#pragma unroll
        for (int i = 0; i < 4; i++)
#pragma unroll
          for (int j = 0; j < 4; j++)
            acc[i][j] = fmaf(a4[i][u], b4[j][u], acc[i][j]);
    }
    __syncthreads();
  }

#pragma unroll
  for (int i = 0; i < 4; i++) {
    const int gm = m0 + ty * 4 + i;
    float res[4];
#pragma unroll
    for (int j = 0; j < 4; j++) {
      const int n = n0 + tx * 4 + j;
      float val = acc[i][j];
      if (EPI == EPI_TANH) {
        val = tanhf(val);
      } else if (EPI == EPI_WDECAY) {
        const float u = bias[n] + val;
        const float sig = 1.f / (1.f + expf(-u));
        val = expf(-0.60653065971263342f * sig);
      } else if (EPI == EPI_SIGBIAS) {
        const float u = bias[n] + val;
        val = 1.f / (1.f + expf(-u));
      } else if (EPI == EPI_SIGMOID) {
        val = 1.f / (1.f + expf(-val));
      } else if (EPI == EPI_VMIX) {
        const float u = bias[n] + val;
        const float sg = 1.f / (1.f + expf(-u));
        const size_t off = (size_t)gm * N + n;
        const float v0v = ex1[off];
        const float vf = ex2[off];
        val = v0v + (vf - v0v) * sg;
      }
      res[j] = val;
    }
    *(float4*)(Cc + (size_t)gm * N + n0 + tx * 4) =
        make_float4(res[0], res[1], res[2], res[3]);
  }
}

// ---------------- mix -> bf16 (3 lambdas) ----------------
__global__ __launch_bounds__(256) void mix3_k(
    const float* __restrict__ x, const float* __restrict__ lr,
    const float* __restrict__ lk, const float* __restrict__ lv,
    short* __restrict__ xr, short* __restrict__ xk, short* __restrict__ xv) {
  const int i = blockIdx.x * 256 + threadIdx.x;
  const int c4 = i % (C_ / 4);
  const int gm = i / (C_ / 4);
  const float4 xa = ((const float4*)x)[i];
  float4 xp = make_float4(0.f, 0.f, 0.f, 0.f);
  if ((gm % T_) != 0) xp = ((const float4*)x)[i - C_ / 4];
  const float4 dx = make_float4(xp.x - xa.x, xp.y - xa.y, xp.z - xa.z, xp.w - xa.w);

  const float4 l1 = ((const float4*)lr)[c4];
  const float4 l2 = ((const float4*)lk)[c4];
  const float4 l3 = ((const float4*)lv)[c4];
  short4 o1 = {bf16b(fmaf(dx.x, l1.x, xa.x)), bf16b(fmaf(dx.y, l1.y, xa.y)),
               bf16b(fmaf(dx.z, l1.z, xa.z)), bf16b(fmaf(dx.w, l1.w, xa.w))};
  short4 o2 = {bf16b(fmaf(dx.x, l2.x, xa.x)), bf16b(fmaf(dx.y, l2.y, xa.y)),
               bf16b(fmaf(dx.z, l2.z, xa.z)), bf16b(fmaf(dx.w, l2.w, xa.w))};
  short4 o3 = {bf16b(fmaf(dx.x, l3.x, xa.x)), bf16b(fmaf(dx.y, l3.y, xa.y)),
               bf16b(fmaf(dx.z, l3.z, xa.z)), bf16b(fmaf(dx.w, l3.w, xa.w))};
  ((short4*)xr)[i] = o1;
  ((short4*)xk)[i] = o2;
  ((short4*)xv)[i] = o3;
}

// ---------------- fp32 -> bf16 convert ----------------
__global__ __launch_bounds__(256) void cvtw_k(const float* __restrict__ in,
                                              short* __restrict__ out, int n4) {
  const int i = blockIdx.x * 256 + threadIdx.x;
  if (i >= n4) return;
  const float4 v = ((const float4*)in)[i];
  short4 o = {bf16b(v.x), bf16b(v.y), bf16b(v.z), bf16b(v.w)};
  ((short4*)out)[i] = o;
}

// ---------------- kk prep ----------------
__global__ __launch_bounds__(256) void kkprep_k(
    const float* __restrict__ k0, const float* __restrict__ a,
    const float* __restrict__ k_k, const float* __restrict__ k_a,
    float* __restrict__ kout, float* __restrict__ z, float* __restrict__ bb) {
  const int wid = threadIdx.x >> 6;
  const int lane = threadIdx.x & 63;
  const size_t hid = (size_t)blockIdx.x * 4 + wid;
  const int h = (int)(hid % H_);
  const size_t idx = hid * 64 + lane;
  const int c = h * 64 + lane;
  const float kv = k0[idx];
  const float av = a[idx];
  const float kk = kv * k_k[c];
  const float ss = wave_sum64(kk * kk);
  const float denom = fmaxf(sqrtf(ss), 1e-12f);
  const float kkn = kk / denom;
  z[idx] = -kkn;
  bb[idx] = kkn * av;
  kout[idx] = kv * (1.f + (av - 1.f) * k_a[c]);
}

// ---------------- WKV-7 recurrence: col-per-lane, depth-8 ring ----------------
// 768 blocks (B*H*16) x 64 threads. Wave = 4 rows x 64 cols; lane = col.
// Ring slot per lane: w,z,b,k,r scalars + wave-uniform v float4 = 9 VGPRs.
#define PFD 8
__global__ __launch_bounds__(64) void wkv7_k(
    const float* __restrict__ rr, const float* __restrict__ dd,
    const float* __restrict__ kk, const float* __restrict__ vv,
    const float* __restrict__ zz, const float* __restrict__ bbv,
    float* __restrict__ yy) {
  const int blk = blockIdx.x;
  const int bh = blk >> 4, rg = blk & 15;
  const int b = bh / H_, h = bh % H_;
  const int lane = threadIdx.x;  // column 0..63
  const int r0 = rg * 4;

  float S0 = 0.f, S1 = 0.f, S2 = 0.f, S3 = 0.f;
  const size_t base0 = ((size_t)b * T_) * C_ + h * 64;

  float wg[PFD], zg[PFD], bg[PFD], kg[PFD], rg_[PFD];
  float4 vg[PFD];
#pragma unroll
  for (int d = 0; d < PFD; d++) {
    const size_t pb = base0 + (size_t)d * C_;
    wg[d] = dd[pb + lane];
    zg[d] = zz[pb + lane];
    bg[d] = bbv[pb + lane];
    kg[d] = kk[pb + lane];
    rg_[d] = rr[pb + lane];
    vg[d] = *(const float4*)(vv + pb + r0);
  }

  for (int t0 = 0; t0 < T_; t0 += PFD) {
#pragma unroll
    for (int d = 0; d < PFD; d++) {
      const int t = t0 + d;
      const float w = wg[d], z = zg[d], bbc = bg[d], kc = kg[d], rc = rg_[d];
      const float4 v4 = vg[d];

      // prefetch step t+PFD into slot d (clamped)
      const int tp = (t + PFD < T_) ? (t + PFD) : (T_ - 1);
      const size_t pb = base0 + (size_t)tp * C_;
      wg[d] = dd[pb + lane];
      zg[d] = zz[pb + lane];
      bg[d] = bbv[pb + lane];
      kg[d] = kk[pb + lane];
      rg_[d] = rr[pb + lane];
      vg[d] = *(const float4*)(vv + pb + r0);

      // sa_r = sum_c S_r[c] * z[c]  (4 interleaved 64-lane butterflies)
      float p0 = S0 * z, p1 = S1 * z, p2 = S2 * z, p3 = S3 * z;
#pragma unroll
      for (int m = 1; m < 64; m <<= 1) {
        p0 += __shfl_xor(p0, m);
        p1 += __shfl_xor(p1, m);
        p2 += __shfl_xor(p2, m);
        p3 += __shfl_xor(p3, m);
      }

      S0 = fmaf(S0, w, fmaf(p0, bbc, v4.x * kc));
      S1 = fmaf(S1, w, fmaf(p1, bbc, v4.y * kc));
      S2 = fmaf(S2, w, fmaf(p2, bbc, v4.z * kc));
      S3 = fmaf(S3, w, fmaf(p3, bbc, v4.w * kc));

      float q0 = S0 * rc, q1 = S1 * rc, q2 = S2 * rc, q3 = S3 * rc;
#pragma unroll
      for (int m = 1; m < 64; m <<= 1) {
        q0 += __shfl_xor(q0, m);
        q1 += __shfl_xor(q1, m);
        q2 += __shfl_xor(q2, m);
        q3 += __shfl_xor(q3, m);
      }
      if (lane == 0) {
        *(float4*)(yy + base0 + (size_t)t * C_ + r0) =
            make_float4(q0, q1, q2, q3);
      }
    }
  }
}

// ---------------- GroupNorm + r_k term + g gating -> bf16 ----------------
__global__ __launch_bounds__(256) void gn_k(
    const float* __restrict__ y, const float* __restrict__ r,
    const float* __restrict__ k, const float* __restrict__ v,
    const float* __restrict__ g, const float* __restrict__ r_k,
    const float* __restrict__ ln_w, const float* __restrict__ ln_b,
    short* __restrict__ ymb) {
  const int wid = threadIdx.x >> 6;
  const int lane = threadIdx.x & 63;
  const size_t hid = (size_t)blockIdx.x * 4 + wid;
  const int h = (int)(hid % H_);
  const size_t idx = hid * 64 + lane;
  const int c = h * 64 + lane;

  const float yv = y[idx];
  const float mu = wave_sum64(yv) * (1.f / 64.f);
  const float sq = wave_sum64(yv * yv) * (1.f / 64.f);
  const float var = sq - mu * mu;
  float yn = (yv - mu) * rsqrtf(var + 0.00064f);
  yn = yn * ln_w[c] + ln_b[c];

  const float s = wave_sum64(r[idx] * k[idx] * r_k[c]);
  yn += s * v[idx];
  ymb[idx] = bf16b(yn * g[idx]);
}

// ---------------- copy ----------------
__global__ __launch_bounds__(256) void copy4_k(const float4* __restrict__ src,
                                               float4* __restrict__ dst, int n4) {
  const int i = blockIdx.x * blockDim.x + threadIdx.x;
  if (i < n4) dst[i] = src[i];
}

// ---------------- host launcher ----------------
template <bool MIX, bool BT, int EPI>
static void launch_gemm(const float* A, const float* Bm, float* Cc, int M,
                        int N, int K, const float* lam, const float* bias,
                        const float* ex1, const float* ex2, hipStream_t s) {
  dim3 grid(N / 64, M / 64), blk(256);
  hipLaunchKernelGGL((gemm_k<MIX, BT, EPI>), grid, blk, 0, s, A, Bm, Cc, M, N,
                     K, lam, bias, ex1, ex2);
}

extern "C" void kernel_launch(void* const* d_in, const int* in_sizes, int n_in,
                              void* d_out, int out_size, void* d_ws,
                              size_t ws_size, hipStream_t stream) {
  const float* x       = (const float*)d_in[0];
  const float* v_first = (const float*)d_in[1];
  const float* lam_r   = (const float*)d_in[2];
  const float* lam_w   = (const float*)d_in[3];
  const float* lam_k   = (const float*)d_in[4];
  const float* lam_v   = (const float*)d_in[5];
  const float* lam_a   = (const float*)d_in[6];
  const float* lam_g   = (const float*)d_in[7];
  const float* w_miu   = (const float*)d_in[8];
  const float* w_A     = (const float*)d_in[9];
  const float* w_B     = (const float*)d_in[10];
  const float* a_miu   = (const float*)d_in[11];
  const float* a_A     = (const float*)d_in[12];
  const float* a_B     = (const float*)d_in[13];
  const float* v_miu   = (const float*)d_in[14];
  const float* v_A     = (const float*)d_in[15];
  const float* v_B     = (const float*)d_in[16];
  const float* g_A     = (const float*)d_in[17];
  const float* g_B     = (const float*)d_in[18];
  const float* k_k     = (const float*)d_in[19];
  const float* k_a     = (const float*)d_in[20];
  const float* r_k     = (const float*)d_in[21];
  const float* W_r     = (const float*)d_in[22];
  const float* W_k     = (const float*)d_in[23];
  const float* W_v     = (const float*)d_in[24];
  const float* W_o     = (const float*)d_in[25];
  const float* ln_w    = (const float*)d_in[26];
  const float* ln_b    = (const float*)d_in[27];

  const int M = B_ * T_;            // 8192
  const size_t S = (size_t)M * C_;  // 6291456

  float* ws   = (float*)d_ws;
  float* r_   = ws + 0 * S;
  float* kbuf = ws + 1 * S;
  float* vbuf = ws + 2 * S;
  float* dec_ = ws + 3 * S;
  float* a_   = ws + 4 * S;
  float* g_   = ws + 5 * S;
  float* z_   = ws + 6 * S;
  float* bb_  = ws + 7 * S;
  float* h_   = ws + 8 * S;                       // M*128 floats
  short* wb   = (short*)(h_ + (size_t)M * 128);   // 4 bf16 weight copies
  float* out  = (float*)d_out;

  short* xr  = (short*)dec_;
  short* xk  = (short*)a_;
  short* xv  = (short*)g_;
  short* ymb = (short*)z_;
  const int WN = C_ * C_;
  short* wrb = wb + 0 * (size_t)WN;
  short* wkb = wb + 1 * (size_t)WN;
  short* wvb = wb + 2 * (size_t)WN;
  short* wob = wb + 3 * (size_t)WN;

  // 1) weights -> bf16
  {
    dim3 blk(256), grid(WN / 4 / 256);
    hipLaunchKernelGGL(cvtw_k, grid, blk, 0, stream, W_r, wrb, WN / 4);
    hipLaunchKernelGGL(cvtw_k, grid, blk, 0, stream, W_k, wkb, WN / 4);
    hipLaunchKernelGGL(cvtw_k, grid, blk, 0, stream, W_v, wvb, WN / 4);
    hipLaunchKernelGGL(cvtw_k, grid, blk, 0, stream, W_o, wob, WN / 4);
  }
  // 2) mixed x -> bf16 (r/k/v lambdas)
  {
    dim3 blk(256), grid((int)(S / 4 / 256));
    hipLaunchKernelGGL(mix3_k, grid, blk, 0, stream, x, lam_r, lam_k, lam_v,
                       xr, xk, xv);
  }
  // 3) big projections via MFMA
  {
    dim3 blk(256), grid(C_ / 128, M / 128);
    hipLaunchKernelGGL(gemm_bf16_k, grid, blk, 0, stream, xr, wrb, r_, M, C_, C_);
    hipLaunchKernelGGL(gemm_bf16_k, grid, blk, 0, stream, xk, wkb, kbuf, M, C_, C_);
    hipLaunchKernelGGL(gemm_bf16_k, grid, blk, 0, stream, xv, wvb, vbuf, M, C_, C_);
  }
  // 4) v low-rank residual gate
  launch_gemm<false, false, EPI_NONE>(vbuf, v_A, h_, M, 64, C_, nullptr, nullptr, nullptr, nullptr, stream);
  launch_gemm<false, false, EPI_VMIX>(h_, v_B, vbuf, M, C_, 64, nullptr, v_miu, vbuf, v_first, stream);
  // 5) decay / a / g paths
  launch_gemm<true, false, EPI_TANH>(x, w_A, h_, M, 64, C_, lam_w, nullptr, nullptr, nullptr, stream);
  launch_gemm<false, false, EPI_WDECAY>(h_, w_B, dec_, M, C_, 64, nullptr, w_miu, nullptr, nullptr, stream);
  launch_gemm<true, false, EPI_NONE>(x, a_A, h_, M, 64, C_, lam_a, nullptr, nullptr, nullptr, stream);
  launch_gemm<false, false, EPI_SIGBIAS>(h_, a_B, a_, M, C_, 64, nullptr, a_miu, nullptr, nullptr, stream);
  launch_gemm<true, false, EPI_SIGMOID>(x, g_A, h_, M, 128, C_, lam_g, nullptr, nullptr, nullptr, stream);
  launch_gemm<false, false, EPI_NONE>(h_, g_B, g_, M, C_, 128, nullptr, nullptr, nullptr, nullptr, stream);
  // 6) kk prep
  {
    dim3 grid((B_ * T_ * H_) / 4), blk(256);
    hipLaunchKernelGGL(kkprep_k, grid, blk, 0, stream, kbuf, a_, k_k, k_a,
                       kbuf, z_, bb_);
  }
  // 7) recurrence -> y (a_ slot)
  {
    dim3 grid(B_ * H_ * 16), blk(64);
    hipLaunchKernelGGL(wkv7_k, grid, blk, 0, stream, r_, dec_, kbuf, vbuf, z_,
                       bb_, a_);
  }
  // 8) groupnorm + rk-term + gate -> ymb (bf16, z_ slot)
  {
    dim3 grid((B_ * T_ * H_) / 4), blk(256);
    hipLaunchKernelGGL(gn_k, grid, blk, 0, stream, a_, r_, kbuf, vbuf, g_, r_k,
                       ln_w, ln_b, ymb);
  }
  // 9) output projection via MFMA
  {
    dim3 blk(256), grid(C_ / 128, M / 128);
    hipLaunchKernelGGL(gemm_bf16_k, grid, blk, 0, stream, ymb, wob, out, M, C_, C_);
  }
  // 10) v_first passthrough
  {
    const int n4 = (int)(S / 4);
    dim3 grid((n4 + 255) / 256), blk(256);
    hipLaunchKernelGGL(copy4_k, grid, blk, 0, stream, (const float4*)v_first,
                       (float4*)(out + S), n4);
  }
}

// Round 5
// 1758.374 us; speedup vs baseline: 1.3757x; 1.3757x over previous
//
#include <hip/hip_runtime.h>
#include <hip/hip_bf16.h>
#include <math.h>

// RWKV-7 TimeMix. R5: LDS-ring pipelined wkv7 fed by a packed operand stream.
// B=4 T=2048 C=768 H=12 N=64, LAYER_ID=1.
//
// Packed record per (b,h,t): 320 floats (1280 B):
//   [0..63]   w  (decay)  fp32   <- decay-GEMM epilogue (packed store)
//   [64..127] z  (-kk)    fp32   <- prep_pack
//   [128..191] b (kk*a)   fp32   <- prep_pack
//   shorts [384..447] k bf16     <- prep_pack
//   shorts [448..511] r bf16     <- MFMA r-GEMM epilogue (packed store)
//   shorts [512..575] v bf16     <- prep_pack
//   shorts [576..639] pad
// Stream: pk[bh][t][320], contiguous per (b,h) -> global_load_lds friendly.

#define B_  4
#define T_  2048
#define C_  768
#define H_  12
#define M_  (B_ * T_)
#define REC_ 320

typedef __attribute__((ext_vector_type(8))) short bf16x8;
typedef __attribute__((ext_vector_type(4))) float f32x4;

#define GLD16(gsrc, ldst)                                                     \
  __builtin_amdgcn_global_load_lds(                                           \
      (const __attribute__((address_space(1))) void*)(gsrc),                  \
      (__attribute__((address_space(3))) void*)(ldst), 16, 0, 0)

static __device__ __forceinline__ float wave_sum64(float v) {
#pragma unroll
  for (int m = 32; m > 0; m >>= 1) v += __shfl_xor(v, m);
  return v;
}

static __device__ __forceinline__ short bf16b(float f) {
  __hip_bfloat16 h = __float2bfloat16(f);
  return *reinterpret_cast<short*>(&h);
}

static __device__ __forceinline__ float ubf(unsigned short u) {
  union { unsigned int i; float f; } c;
  c.i = ((unsigned int)u) << 16;
  return c.f;
}

// ---------------- bf16 MFMA GEMM ----------------
// C = A[M,K]bf16 @ Bw[N,K]bf16^T. PACKR=false: fp32 C[M,N]. PACKR=true:
// bf16 scatter into packed-record r-slot.
template <bool PACKR>
__global__ __launch_bounds__(256) void gemm_bf16_k(
    const short* __restrict__ A, const short* __restrict__ Bw,
    float* __restrict__ C, int M, int N, int K) {
  __shared__ short As[128 * 32];
  __shared__ short Bs[128 * 32];
  const int tid = threadIdx.x;
  const int wave = tid >> 6, lane = tid & 63;
  const int m0 = blockIdx.y * 128, n0 = blockIdx.x * 128;
  const int wm = (wave >> 1) * 64, wn = (wave & 1) * 64;
  const int fr = lane & 15, fk = (lane >> 4) * 8;

  f32x4 acc[4][4];
#pragma unroll
  for (int i = 0; i < 4; i++)
#pragma unroll
    for (int j = 0; j < 4; j++) acc[i][j] = (f32x4){0.f, 0.f, 0.f, 0.f};

  const int srow = tid >> 2, scol = (tid & 3) * 8;
  const short* gA = A + (size_t)(m0 + srow) * K + scol;
  const short* gB = Bw + (size_t)(n0 + srow) * K + scol;
  short* lA0 = &As[wave * 512];
  short* lA1 = &As[2048 + wave * 512];
  short* lB0 = &Bs[wave * 512];
  short* lB1 = &Bs[2048 + wave * 512];

  for (int k0 = 0; k0 < K; k0 += 32) {
    GLD16(gA + k0, lA0);
    GLD16(gA + (size_t)64 * K + k0, lA1);
    GLD16(gB + k0, lB0);
    GLD16(gB + (size_t)64 * K + k0, lB1);
    __syncthreads();

    bf16x8 af[4], bf[4];
#pragma unroll
    for (int i = 0; i < 4; i++)
      af[i] = *(const bf16x8*)&As[(wm + i * 16 + fr) * 32 + fk];
#pragma unroll
    for (int j = 0; j < 4; j++)
      bf[j] = *(const bf16x8*)&Bs[(wn + j * 16 + fr) * 32 + fk];
#pragma unroll
    for (int i = 0; i < 4; i++)
#pragma unroll
      for (int j = 0; j < 4; j++)
        acc[i][j] =
            __builtin_amdgcn_mfma_f32_16x16x32_bf16(af[i], bf[j], acc[i][j], 0, 0, 0);
    __syncthreads();
  }

  if (PACKR) {
#pragma unroll
    for (int i = 0; i < 4; i++) {
      const int gm0 = m0 + wm + i * 16 + (lane >> 4) * 4;
#pragma unroll
      for (int j = 0; j < 4; j++) {
        const int gn = n0 + wn + j * 16 + fr;
        const int hh = gn >> 6, cc = gn & 63;
#pragma unroll
        for (int rix = 0; rix < 4; rix++) {
          const int gm = gm0 + rix;
          const int bb = gm >> 11, tt = gm & (T_ - 1);
          const size_t rec = ((size_t)bb * H_ + hh) * T_ + tt;
          ((short*)C)[rec * (2 * REC_) + 448 + cc] = bf16b(acc[i][j][rix]);
        }
      }
    }
  } else {
#pragma unroll
    for (int i = 0; i < 4; i++) {
      const int gm = m0 + wm + i * 16 + (lane >> 4) * 4;
#pragma unroll
      for (int j = 0; j < 4; j++) {
        const int gn = n0 + wn + j * 16 + fr;
#pragma unroll
        for (int rix = 0; rix < 4; rix++)
          C[(size_t)(gm + rix) * N + gn] = acc[i][j][rix];
      }
    }
  }
}

// ---------------- fp32 GEMM (small paths) ----------------
enum { EPI_NONE = 0, EPI_TANH, EPI_WDECAY, EPI_SIGBIAS, EPI_SIGMOID, EPI_VMIX };

template <bool MIX, int EPI>
__global__ __launch_bounds__(256) void gemm_k(
    const float* __restrict__ A, const float* __restrict__ Bm,
    float* __restrict__ Cc, int M, int N, int K,
    const float* __restrict__ lam, const float* __restrict__ bias,
    const float* __restrict__ ex1, const float* __restrict__ ex2) {
  __shared__ float As[64][20];
  __shared__ float Bs[64][20];
  const int tid = threadIdx.x;
  const int n0 = blockIdx.x * 64;
  const int m0 = blockIdx.y * 64;
  const int tx = tid & 15, ty = tid >> 4;

  float acc[4][4];
#pragma unroll
  for (int i = 0; i < 4; i++)
#pragma unroll
    for (int j = 0; j < 4; j++) acc[i][j] = 0.f;

  const int lm = tid >> 2;
  const int lk4 = (tid & 3) * 4;

  for (int k0 = 0; k0 < K; k0 += 16) {
    {
      const int gm = m0 + lm;
      const float* ap = A + (size_t)gm * K + k0 + lk4;
      float4 xa = *(const float4*)ap;
      if (MIX) {
        float4 xp = make_float4(0.f, 0.f, 0.f, 0.f);
        if ((gm % T_) != 0) xp = *(const float4*)(ap - K);
        const float4 l4 = *(const float4*)(lam + k0 + lk4);
        xa.x += (xp.x - xa.x) * l4.x;
        xa.y += (xp.y - xa.y) * l4.y;
        xa.z += (xp.z - xa.z) * l4.z;
        xa.w += (xp.w - xa.w) * l4.w;
      }
      *(float4*)&As[lm][lk4] = xa;
    }
    {
      const int kl = tid >> 4;
      const int nl = (tid & 15) * 4;
      const float4 bv = *(const float4*)(Bm + (size_t)(k0 + kl) * N + n0 + nl);
      Bs[nl + 0][kl] = bv.x;
      Bs[nl + 1][kl] = bv.y;
      Bs[nl + 2][kl] = bv.z;
      Bs[nl + 3][kl] = bv.w;
    }
    __syncthreads();

#pragma unroll
    for (int kb = 0; kb < 16; kb += 4) {
      float a4[4][4], b4[4][4];
#pragma unroll
      for (int i = 0; i < 4; i++) {
        const float4 t = *(const float4*)&As[ty * 4 + i][kb];
        a4[i][0] = t.x; a4[i][1] = t.y; a4[i][2] = t.z; a4[i][3] = t.w;
      }
#pragma unroll
      for (int j = 0; j < 4; j++) {
        const float4 t = *(const float4*)&Bs[tx * 4 + j][kb];
        b4[j][0] = t.x; b4[j][1] = t.y; b4[j][2] = t.z; b4[j][3] = t.w;
      }
#pragma unroll
      for (int u = 0; u < 4; u++)
#pragma unroll
        for (int i = 0; i < 4; i++)
#pragma unroll
          for (int j = 0; j < 4; j++)
            acc[i][j] = fmaf(a4[i][u], b4[j][u], acc[i][j]);
    }
    __syncthreads();
  }

#pragma unroll
  for (int i = 0; i < 4; i++) {
    const int gm = m0 + ty * 4 + i;
    float res[4];
#pragma unroll
    for (int j = 0; j < 4; j++) {
      const int n = n0 + tx * 4 + j;
      float val = acc[i][j];
      if (EPI == EPI_TANH) {
        val = tanhf(val);
      } else if (EPI == EPI_WDECAY) {
        const float u = bias[n] + val;
        const float sig = 1.f / (1.f + expf(-u));
        val = expf(-0.60653065971263342f * sig);
      } else if (EPI == EPI_SIGBIAS) {
        const float u = bias[n] + val;
        val = 1.f / (1.f + expf(-u));
      } else if (EPI == EPI_SIGMOID) {
        val = 1.f / (1.f + expf(-val));
      } else if (EPI == EPI_VMIX) {
        const float u = bias[n] + val;
        const float sg = 1.f / (1.f + expf(-u));
        const size_t off = (size_t)gm * N + n;
        const float v0v = ex1[off];
        const float vf = ex2[off];
        val = v0v + (vf - v0v) * sg;
      }
      res[j] = val;
    }
    if (EPI == EPI_WDECAY) {
      // packed store into w-slot of the record stream
      const int bb = gm >> 11, tt = gm & (T_ - 1);
      const int hh = (n0 + tx * 4) >> 6;
      const size_t rec = ((size_t)bb * H_ + hh) * T_ + tt;
      *(float4*)(Cc + rec * REC_ + ((n0 + tx * 4) & 63)) =
          make_float4(res[0], res[1], res[2], res[3]);
    } else {
      *(float4*)(Cc + (size_t)gm * N + n0 + tx * 4) =
          make_float4(res[0], res[1], res[2], res[3]);
    }
  }
}

// ---------------- mix -> bf16 (3 lambdas) ----------------
__global__ __launch_bounds__(256) void mix3_k(
    const float* __restrict__ x, const float* __restrict__ lr,
    const float* __restrict__ lk, const float* __restrict__ lv,
    short* __restrict__ xr, short* __restrict__ xk, short* __restrict__ xv) {
  const int i = blockIdx.x * 256 + threadIdx.x;
  const int c4 = i % (C_ / 4);
  const int gm = i / (C_ / 4);
  const float4 xa = ((const float4*)x)[i];
  float4 xp = make_float4(0.f, 0.f, 0.f, 0.f);
  if ((gm % T_) != 0) xp = ((const float4*)x)[i - C_ / 4];
  const float4 dx = make_float4(xp.x - xa.x, xp.y - xa.y, xp.z - xa.z, xp.w - xa.w);

  const float4 l1 = ((const float4*)lr)[c4];
  const float4 l2 = ((const float4*)lk)[c4];
  const float4 l3 = ((const float4*)lv)[c4];
  short4 o1 = {bf16b(fmaf(dx.x, l1.x, xa.x)), bf16b(fmaf(dx.y, l1.y, xa.y)),
               bf16b(fmaf(dx.z, l1.z, xa.z)), bf16b(fmaf(dx.w, l1.w, xa.w))};
  short4 o2 = {bf16b(fmaf(dx.x, l2.x, xa.x)), bf16b(fmaf(dx.y, l2.y, xa.y)),
               bf16b(fmaf(dx.z, l2.z, xa.z)), bf16b(fmaf(dx.w, l2.w, xa.w))};
  short4 o3 = {bf16b(fmaf(dx.x, l3.x, xa.x)), bf16b(fmaf(dx.y, l3.y, xa.y)),
               bf16b(fmaf(dx.z, l3.z, xa.z)), bf16b(fmaf(dx.w, l3.w, xa.w))};
  ((short4*)xr)[i] = o1;
  ((short4*)xk)[i] = o2;
  ((short4*)xv)[i] = o3;
}

// ---------------- fp32 -> bf16 convert ----------------
__global__ __launch_bounds__(256) void cvtw_k(const float* __restrict__ in,
                                              short* __restrict__ out, int n4) {
  const int i = blockIdx.x * 256 + threadIdx.x;
  if (i >= n4) return;
  const float4 v = ((const float4*)in)[i];
  short4 o = {bf16b(v.x), bf16b(v.y), bf16b(v.z), bf16b(v.w)};
  ((short4*)out)[i] = o;
}

// ---------------- prep + pack: z,b,k,v slots of the record ----------------
__global__ __launch_bounds__(256) void prep_pack_k(
    const float* __restrict__ k0, const float* __restrict__ a,
    const float* __restrict__ v, const float* __restrict__ k_k,
    const float* __restrict__ k_a, float* __restrict__ pk) {
  const int wid = threadIdx.x >> 6;
  const int lane = threadIdx.x & 63;
  const size_t hid = (size_t)blockIdx.x * 4 + wid;  // (b*T+t)*H + h
  const int b = (int)(hid / ((size_t)T_ * H_));
  const int t = (int)((hid / H_) % T_);
  const int h = (int)(hid % H_);
  const size_t idx = hid * 64 + lane;
  const int c = h * 64 + lane;

  const float kv = k0[idx];
  const float av = a[idx];
  const float kk = kv * k_k[c];
  const float ss = wave_sum64(kk * kk);
  const float denom = fmaxf(sqrtf(ss), 1e-12f);
  const float kkn = kk / denom;

  const size_t rec = ((size_t)b * H_ + h) * T_ + t;
  float* pr = pk + rec * REC_;
  pr[64 + lane] = -kkn;
  pr[128 + lane] = kkn * av;
  short* ps = (short*)pr;
  ps[384 + lane] = bf16b(kv * (1.f + (av - 1.f) * k_a[c]));
  ps[512 + lane] = bf16b(v[idx]);
}

// ---------------- WKV-7: LDS-ring pipelined recurrence ----------------
// 768 blocks (bh*16 rowgroups) x 64 threads. Wave = 4 rows x 16-lane teams,
// lane holds 4 cols. LDS ring = 4 quads x 4 steps x 320 floats (20 KB).
// 5 global_load_lds dwordx4 per quad, 3 quads in flight, vmcnt(15) gate.
__global__ __launch_bounds__(64) void wkv7_k(const float* __restrict__ pk,
                                             float* __restrict__ yy) {
  const int bh = blockIdx.x >> 4, rg = blockIdx.x & 15;
  const int lane = threadIdx.x;
  const int l16 = lane & 15, team = lane >> 4;
  const int cb = l16 * 4;
  const int row = rg * 4 + team;
  const float* pkb = pk + (size_t)bh * T_ * REC_ + lane * 4;
  __shared__ float ring[4 * 4 * REC_];

#pragma unroll
  for (int q = 0; q < 3; q++) {
    const float* g = pkb + (size_t)q * (4 * REC_);
    float* l = &ring[(q & 3) * (4 * REC_)];
#pragma unroll
    for (int i = 0; i < 5; i++) GLD16(g + i * 256, l + i * 256);
  }

  float S0 = 0.f, S1 = 0.f, S2 = 0.f, S3 = 0.f;
  const int b = bh / H_, h = bh % H_;
  float* yb = yy + ((size_t)b * T_) * C_ + h * 64 + row;

  const int NQ = T_ / 4;
  for (int q = 0; q < NQ; q++) {
    if (q + 3 < NQ) {
      const float* g = pkb + (size_t)(q + 3) * (4 * REC_);
      float* l = &ring[((q + 3) & 3) * (4 * REC_)];
#pragma unroll
      for (int i = 0; i < 5; i++) GLD16(g + i * 256, l + i * 256);
      asm volatile("s_waitcnt vmcnt(15)" ::: "memory");
    } else {
      asm volatile("s_waitcnt vmcnt(0)" ::: "memory");
    }
    const float* rb = &ring[(q & 3) * (4 * REC_)];
#pragma unroll
    for (int d = 0; d < 4; d++) {
      const float* rec = rb + d * REC_;
      const float4 w4 = *(const float4*)(rec + cb);
      const float4 z4 = *(const float4*)(rec + 64 + cb);
      const float4 b4 = *(const float4*)(rec + 128 + cb);
      const ushort* rs = (const ushort*)rec;
      const ushort4 ku = *(const ushort4*)(rs + 384 + cb);
      const ushort4 ru = *(const ushort4*)(rs + 448 + cb);
      const float vi = ubf(rs[512 + row]);

      float sa = S0 * z4.x;
      sa = fmaf(S1, z4.y, sa);
      sa = fmaf(S2, z4.z, sa);
      sa = fmaf(S3, z4.w, sa);
      sa += __shfl_xor(sa, 1);
      sa += __shfl_xor(sa, 2);
      sa += __shfl_xor(sa, 4);
      sa += __shfl_xor(sa, 8);

      S0 = fmaf(S0, w4.x, fmaf(sa, b4.x, vi * ubf(ku.x)));
      S1 = fmaf(S1, w4.y, fmaf(sa, b4.y, vi * ubf(ku.y)));
      S2 = fmaf(S2, w4.z, fmaf(sa, b4.z, vi * ubf(ku.z)));
      S3 = fmaf(S3, w4.w, fmaf(sa, b4.w, vi * ubf(ku.w)));

      float yp = S0 * ubf(ru.x);
      yp = fmaf(S1, ubf(ru.y), yp);
      yp = fmaf(S2, ubf(ru.z), yp);
      yp = fmaf(S3, ubf(ru.w), yp);
      yp += __shfl_xor(yp, 1);
      yp += __shfl_xor(yp, 2);
      yp += __shfl_xor(yp, 4);
      yp += __shfl_xor(yp, 8);
      if (l16 == 0) yb[(size_t)(q * 4 + d) * C_] = yp;
    }
  }
}

// ---------------- GroupNorm + r_k term + g gating -> bf16 ----------------
__global__ __launch_bounds__(256) void gn_k(
    const float* __restrict__ y, const float* __restrict__ pk,
    const float* __restrict__ v, const float* __restrict__ g,
    const float* __restrict__ r_k, const float* __restrict__ ln_w,
    const float* __restrict__ ln_b, short* __restrict__ ymb) {
  const int wid = threadIdx.x >> 6;
  const int lane = threadIdx.x & 63;
  const size_t hid = (size_t)blockIdx.x * 4 + wid;
  const int b = (int)(hid / ((size_t)T_ * H_));
  const int t = (int)((hid / H_) % T_);
  const int h = (int)(hid % H_);
  const size_t idx = hid * 64 + lane;
  const int c = h * 64 + lane;

  const float yv = y[idx];
  const float mu = wave_sum64(yv) * (1.f / 64.f);
  const float sq = wave_sum64(yv * yv) * (1.f / 64.f);
  const float var = sq - mu * mu;
  float yn = (yv - mu) * rsqrtf(var + 0.00064f);
  yn = yn * ln_w[c] + ln_b[c];

  const size_t rec = ((size_t)b * H_ + h) * T_ + t;
  const short* ps = (const short*)(pk + rec * REC_);
  const float kf = ubf(((const ushort*)ps)[384 + lane]);
  const float rf = ubf(((const ushort*)ps)[448 + lane]);
  const float s = wave_sum64(rf * kf * r_k[c]);
  yn += s * v[idx];
  ymb[idx] = bf16b(yn * g[idx]);
}

// ---------------- copy ----------------
__global__ __launch_bounds__(256) void copy4_k(const float4* __restrict__ src,
                                               float4* __restrict__ dst, int n4) {
  const int i = blockIdx.x * blockDim.x + threadIdx.x;
  if (i < n4) dst[i] = src[i];
}

// ---------------- host launcher ----------------
template <bool MIX, int EPI>
static void launch_gemm(const float* A, const float* Bm, float* Cc, int M,
                        int N, int K, const float* lam, const float* bias,
                        const float* ex1, const float* ex2, hipStream_t s) {
  dim3 grid(N / 64, M / 64), blk(256);
  hipLaunchKernelGGL((gemm_k<MIX, EPI>), grid, blk, 0, s, A, Bm, Cc, M, N, K,
                     lam, bias, ex1, ex2);
}

extern "C" void kernel_launch(void* const* d_in, const int* in_sizes, int n_in,
                              void* d_out, int out_size, void* d_ws,
                              size_t ws_size, hipStream_t stream) {
  const float* x       = (const float*)d_in[0];
  const float* v_first = (const float*)d_in[1];
  const float* lam_r   = (const float*)d_in[2];
  const float* lam_w   = (const float*)d_in[3];
  const float* lam_k   = (const float*)d_in[4];
  const float* lam_v   = (const float*)d_in[5];
  const float* lam_a   = (const float*)d_in[6];
  const float* lam_g   = (const float*)d_in[7];
  const float* w_miu   = (const float*)d_in[8];
  const float* w_A     = (const float*)d_in[9];
  const float* w_B     = (const float*)d_in[10];
  const float* a_miu   = (const float*)d_in[11];
  const float* a_A     = (const float*)d_in[12];
  const float* a_B     = (const float*)d_in[13];
  const float* v_miu   = (const float*)d_in[14];
  const float* v_A     = (const float*)d_in[15];
  const float* v_B     = (const float*)d_in[16];
  const float* g_A     = (const float*)d_in[17];
  const float* g_B     = (const float*)d_in[18];
  const float* k_k     = (const float*)d_in[19];
  const float* k_a     = (const float*)d_in[20];
  const float* r_k     = (const float*)d_in[21];
  const float* W_r     = (const float*)d_in[22];
  const float* W_k     = (const float*)d_in[23];
  const float* W_v     = (const float*)d_in[24];
  const float* W_o     = (const float*)d_in[25];
  const float* ln_w    = (const float*)d_in[26];
  const float* ln_b    = (const float*)d_in[27];

  const int M = M_;                 // 8192
  const size_t S = (size_t)M * C_;  // 6291456
  const int WN = C_ * C_;           // 589824

  // workspace layout (floats): kbuf,vbuf,a_,g_ (4 S-slots), h_, wb, xr, pk.
  // xk/xv overlay the start of pk (dead before the first pk write).
  float* ws   = (float*)d_ws;
  float* kbuf = ws;                                   // k0; ymb later
  float* vbuf = ws + S;
  float* a_   = ws + 2 * S;                           // a; then y
  float* g_   = ws + 3 * S;
  float* h_   = ws + 4 * S;                           // M*128 floats
  short* wb   = (short*)(h_ + (size_t)M * 128);       // 4*WN shorts
  short* xr   = wb + 4 * (size_t)WN;                  // S shorts
  float* pk   = (float*)(xr + S);                     // 48*2048*320 floats
  short* xk   = (short*)pk;                           // overlay (transient)
  short* xv   = (short*)pk + S;                       // overlay (transient)
  short* ymb  = (short*)kbuf;
  float* out  = (float*)d_out;

  short* wrb = wb + 0 * (size_t)WN;
  short* wkb = wb + 1 * (size_t)WN;
  short* wvb = wb + 2 * (size_t)WN;
  short* wob = wb + 3 * (size_t)WN;

  // 1) weights -> bf16
  {
    dim3 blk(256), grid(WN / 4 / 256);
    hipLaunchKernelGGL(cvtw_k, grid, blk, 0, stream, W_r, wrb, WN / 4);
    hipLaunchKernelGGL(cvtw_k, grid, blk, 0, stream, W_k, wkb, WN / 4);
    hipLaunchKernelGGL(cvtw_k, grid, blk, 0, stream, W_v, wvb, WN / 4);
    hipLaunchKernelGGL(cvtw_k, grid, blk, 0, stream, W_o, wob, WN / 4);
  }
  // 2) mixed x -> bf16
  {
    dim3 blk(256), grid((int)(S / 4 / 256));
    hipLaunchKernelGGL(mix3_k, grid, blk, 0, stream, x, lam_r, lam_k, lam_v,
                       xr, xk, xv);
  }
  // 3) k,v projections (xk/xv consumed -> overlay region free after)
  {
    dim3 blk(256), grid(C_ / 128, M / 128);
    hipLaunchKernelGGL((gemm_bf16_k<false>), grid, blk, 0, stream, xk, wkb, kbuf, M, C_, C_);
    hipLaunchKernelGGL((gemm_bf16_k<false>), grid, blk, 0, stream, xv, wvb, vbuf, M, C_, C_);
  }
  // 4) v low-rank residual gate
  launch_gemm<false, EPI_NONE>(vbuf, v_A, h_, M, 64, C_, nullptr, nullptr, nullptr, nullptr, stream);
  launch_gemm<false, EPI_VMIX>(h_, v_B, vbuf, M, C_, 64, nullptr, v_miu, vbuf, v_first, stream);
  // 5) r projection -> packed r-slot (first pk write)
  {
    dim3 blk(256), grid(C_ / 128, M / 128);
    hipLaunchKernelGGL((gemm_bf16_k<true>), grid, blk, 0, stream, xr, wrb, (float*)pk, M, C_, C_);
  }
  // 6) decay path -> packed w-slot
  launch_gemm<true, EPI_TANH>(x, w_A, h_, M, 64, C_, lam_w, nullptr, nullptr, nullptr, stream);
  launch_gemm<false, EPI_WDECAY>(h_, w_B, pk, M, C_, 64, nullptr, w_miu, nullptr, nullptr, stream);
  // 7) a path
  launch_gemm<true, EPI_NONE>(x, a_A, h_, M, 64, C_, lam_a, nullptr, nullptr, nullptr, stream);
  launch_gemm<false, EPI_SIGBIAS>(h_, a_B, a_, M, C_, 64, nullptr, a_miu, nullptr, nullptr, stream);
  // 8) g path
  launch_gemm<true, EPI_SIGMOID>(x, g_A, h_, M, 128, C_, lam_g, nullptr, nullptr, nullptr, stream);
  launch_gemm<false, EPI_NONE>(h_, g_B, g_, M, C_, 128, nullptr, nullptr, nullptr, nullptr, stream);
  // 9) prep + pack z,b,k,v slots
  {
    dim3 grid((B_ * T_ * H_) / 4), blk(256);
    hipLaunchKernelGGL(prep_pack_k, grid, blk, 0, stream, kbuf, a_, vbuf, k_k,
                       k_a, pk);
  }
  // 10) recurrence -> y (a_ slot)
  {
    dim3 grid(B_ * H_ * 16), blk(64);
    hipLaunchKernelGGL(wkv7_k, grid, blk, 0, stream, pk, a_);
  }
  // 11) groupnorm + rk-term + gate -> ymb (kbuf region)
  {
    dim3 grid((B_ * T_ * H_) / 4), blk(256);
    hipLaunchKernelGGL(gn_k, grid, blk, 0, stream, a_, pk, vbuf, g_, r_k,
                       ln_w, ln_b, ymb);
  }
  // 12) output projection
  {
    dim3 blk(256), grid(C_ / 128, M / 128);
    hipLaunchKernelGGL((gemm_bf16_k<false>), grid, blk, 0, stream, ymb, wob, out, M, C_, C_);
  }
  // 13) v_first passthrough
  {
    const int n4 = (int)(S / 4);
    dim3 grid((n4 + 255) / 256), blk(256);
    hipLaunchKernelGGL(copy4_k, grid, blk, 0, stream, (const float4*)v_first,
                       (float4*)(out + S), n4);
  }
}

// Round 6
// 1692.993 us; speedup vs baseline: 1.4288x; 1.0386x over previous
//
#include <hip/hip_runtime.h>
#include <hip/hip_bf16.h>
#include <math.h>

// RWKV-7 TimeMix. R6: store-free wkv7 loop (ds_write ybuf + batched flush),
// 8-way row split; batched small GEMMs (blockIdx.z). B=4 T=2048 C=768 H=12.
//
// Packed record per (b,h,t): 320 floats (1280 B):
//   [0..63] w fp32 | [64..127] z fp32 | [128..191] b fp32
//   shorts: [384..447] k bf16 | [448..511] r bf16 | [512..575] v bf16 | pad

#define B_  4
#define T_  2048
#define C_  768
#define H_  12
#define M_  (B_ * T_)
#define REC_ 320

typedef __attribute__((ext_vector_type(8))) short bf16x8;
typedef __attribute__((ext_vector_type(4))) float f32x4;

#define GLD16(gsrc, ldst)                                                     \
  __builtin_amdgcn_global_load_lds(                                           \
      (const __attribute__((address_space(1))) void*)(gsrc),                  \
      (__attribute__((address_space(3))) void*)(ldst), 16, 0, 0)

static __device__ __forceinline__ float wave_sum64(float v) {
#pragma unroll
  for (int m = 32; m > 0; m >>= 1) v += __shfl_xor(v, m);
  return v;
}

static __device__ __forceinline__ short bf16b(float f) {
  __hip_bfloat16 h = __float2bfloat16(f);
  return *reinterpret_cast<short*>(&h);
}

static __device__ __forceinline__ float ubf(unsigned short u) {
  union { unsigned int i; float f; } c;
  c.i = ((unsigned int)u) << 16;
  return c.f;
}

// ---------------- bf16 MFMA GEMM ----------------
template <bool PACKR>
__global__ __launch_bounds__(256) void gemm_bf16_k(
    const short* __restrict__ A, const short* __restrict__ Bw,
    float* __restrict__ C, int M, int N, int K) {
  __shared__ short As[128 * 32];
  __shared__ short Bs[128 * 32];
  const int tid = threadIdx.x;
  const int wave = tid >> 6, lane = tid & 63;
  const int m0 = blockIdx.y * 128, n0 = blockIdx.x * 128;
  const int wm = (wave >> 1) * 64, wn = (wave & 1) * 64;
  const int fr = lane & 15, fk = (lane >> 4) * 8;

  f32x4 acc[4][4];
#pragma unroll
  for (int i = 0; i < 4; i++)
#pragma unroll
    for (int j = 0; j < 4; j++) acc[i][j] = (f32x4){0.f, 0.f, 0.f, 0.f};

  const int srow = tid >> 2, scol = (tid & 3) * 8;
  const short* gA = A + (size_t)(m0 + srow) * K + scol;
  const short* gB = Bw + (size_t)(n0 + srow) * K + scol;
  short* lA0 = &As[wave * 512];
  short* lA1 = &As[2048 + wave * 512];
  short* lB0 = &Bs[wave * 512];
  short* lB1 = &Bs[2048 + wave * 512];

  for (int k0 = 0; k0 < K; k0 += 32) {
    GLD16(gA + k0, lA0);
    GLD16(gA + (size_t)64 * K + k0, lA1);
    GLD16(gB + k0, lB0);
    GLD16(gB + (size_t)64 * K + k0, lB1);
    __syncthreads();

    bf16x8 af[4], bf[4];
#pragma unroll
    for (int i = 0; i < 4; i++)
      af[i] = *(const bf16x8*)&As[(wm + i * 16 + fr) * 32 + fk];
#pragma unroll
    for (int j = 0; j < 4; j++)
      bf[j] = *(const bf16x8*)&Bs[(wn + j * 16 + fr) * 32 + fk];
#pragma unroll
    for (int i = 0; i < 4; i++)
#pragma unroll
      for (int j = 0; j < 4; j++)
        acc[i][j] =
            __builtin_amdgcn_mfma_f32_16x16x32_bf16(af[i], bf[j], acc[i][j], 0, 0, 0);
    __syncthreads();
  }

  if (PACKR) {
#pragma unroll
    for (int i = 0; i < 4; i++) {
      const int gm0 = m0 + wm + i * 16 + (lane >> 4) * 4;
#pragma unroll
      for (int j = 0; j < 4; j++) {
        const int gn = n0 + wn + j * 16 + fr;
        const int hh = gn >> 6, cc = gn & 63;
#pragma unroll
        for (int rix = 0; rix < 4; rix++) {
          const int gm = gm0 + rix;
          const int bb = gm >> 11, tt = gm & (T_ - 1);
          const size_t rec = ((size_t)bb * H_ + hh) * T_ + tt;
          ((short*)C)[rec * (2 * REC_) + 448 + cc] = bf16b(acc[i][j][rix]);
        }
      }
    }
  } else {
#pragma unroll
    for (int i = 0; i < 4; i++) {
      const int gm = m0 + wm + i * 16 + (lane >> 4) * 4;
#pragma unroll
      for (int j = 0; j < 4; j++) {
        const int gn = n0 + wn + j * 16 + fr;
#pragma unroll
        for (int rix = 0; rix < 4; rix++)
          C[(size_t)(gm + rix) * N + gn] = acc[i][j][rix];
      }
    }
  }
}

// ---------------- batched fp32 GEMM (small paths) ----------------
enum { EPI_NONE = 0, EPI_TANH, EPI_WDECAY, EPI_SIGBIAS, EPI_SIGMOID, EPI_VMIX };

struct BGParam {
  const float* A; const float* Bm; float* C;
  const float* lam; const float* bias; const float* ex1; const float* ex2;
  int N, K, mix, epi;
};
struct BG4 { BGParam p[4]; };

__global__ __launch_bounds__(256) void gemm_small_k(BG4 all) {
  const BGParam pp = all.p[blockIdx.z];
  const int N = pp.N, K = pp.K;
  const int n0 = blockIdx.x * 64;
  if (n0 >= N) return;
  const int m0 = blockIdx.y * 64;

  __shared__ float As[64][20];
  __shared__ float Bs[64][20];
  const int tid = threadIdx.x;
  const int tx = tid & 15, ty = tid >> 4;

  float acc[4][4];
#pragma unroll
  for (int i = 0; i < 4; i++)
#pragma unroll
    for (int j = 0; j < 4; j++) acc[i][j] = 0.f;

  const int lm = tid >> 2;
  const int lk4 = (tid & 3) * 4;

  for (int k0 = 0; k0 < K; k0 += 16) {
    {
      const int gm = m0 + lm;
      const float* ap = pp.A + (size_t)gm * K + k0 + lk4;
      float4 xa = *(const float4*)ap;
      if (pp.mix) {
        float4 xp = make_float4(0.f, 0.f, 0.f, 0.f);
        if ((gm % T_) != 0) xp = *(const float4*)(ap - K);
        const float4 l4 = *(const float4*)(pp.lam + k0 + lk4);
        xa.x += (xp.x - xa.x) * l4.x;
        xa.y += (xp.y - xa.y) * l4.y;
        xa.z += (xp.z - xa.z) * l4.z;
        xa.w += (xp.w - xa.w) * l4.w;
      }
      *(float4*)&As[lm][lk4] = xa;
    }
    {
      const int kl = tid >> 4;
      const int nl = (tid & 15) * 4;
      const float4 bv = *(const float4*)(pp.Bm + (size_t)(k0 + kl) * N + n0 + nl);
      Bs[nl + 0][kl] = bv.x;
      Bs[nl + 1][kl] = bv.y;
      Bs[nl + 2][kl] = bv.z;
      Bs[nl + 3][kl] = bv.w;
    }
    __syncthreads();

#pragma unroll
    for (int kb = 0; kb < 16; kb += 4) {
      float a4[4][4], b4[4][4];
#pragma unroll
      for (int i = 0; i < 4; i++) {
        const float4 t = *(const float4*)&As[ty * 4 + i][kb];
        a4[i][0] = t.x; a4[i][1] = t.y; a4[i][2] = t.z; a4[i][3] = t.w;
      }
#pragma unroll
      for (int j = 0; j < 4; j++) {
        const float4 t = *(const float4*)&Bs[tx * 4 + j][kb];
        b4[j][0] = t.x; b4[j][1] = t.y; b4[j][2] = t.z; b4[j][3] = t.w;
      }
#pragma unroll
      for (int u = 0; u < 4; u++)
#pragma unroll
        for (int i = 0; i < 4; i++)
#pragma unroll
          for (int j = 0; j < 4; j++)
            acc[i][j] = fmaf(a4[i][u], b4[j][u], acc[i][j]);
    }
    __syncthreads();
  }

  const int epi = pp.epi;
#pragma unroll
  for (int i = 0; i < 4; i++) {
    const int gm = m0 + ty * 4 + i;
    float res[4];
#pragma unroll
    for (int j = 0; j < 4; j++) {
      const int n = n0 + tx * 4 + j;
      float val = acc[i][j];
      if (epi == EPI_TANH) {
        val = tanhf(val);
      } else if (epi == EPI_WDECAY) {
        const float u = pp.bias[n] + val;
        const float sig = 1.f / (1.f + expf(-u));
        val = expf(-0.60653065971263342f * sig);
      } else if (epi == EPI_SIGBIAS) {
        const float u = pp.bias[n] + val;
        val = 1.f / (1.f + expf(-u));
      } else if (epi == EPI_SIGMOID) {
        val = 1.f / (1.f + expf(-val));
      } else if (epi == EPI_VMIX) {
        const float u = pp.bias[n] + val;
        const float sg = 1.f / (1.f + expf(-u));
        const size_t off = (size_t)gm * N + n;
        const float v0v = pp.ex1[off];
        const float vf = pp.ex2[off];
        val = v0v + (vf - v0v) * sg;
      }
      res[j] = val;
    }
    if (epi == EPI_WDECAY) {
      const int bb = gm >> 11, tt = gm & (T_ - 1);
      const int hh = (n0 + tx * 4) >> 6;
      const size_t rec = ((size_t)bb * H_ + hh) * T_ + tt;
      *(float4*)(pp.C + rec * REC_ + ((n0 + tx * 4) & 63)) =
          make_float4(res[0], res[1], res[2], res[3]);
    } else {
      *(float4*)(pp.C + (size_t)gm * N + n0 + tx * 4) =
          make_float4(res[0], res[1], res[2], res[3]);
    }
  }
}

// ---------------- mix -> bf16 (3 lambdas) ----------------
__global__ __launch_bounds__(256) void mix3_k(
    const float* __restrict__ x, const float* __restrict__ lr,
    const float* __restrict__ lk, const float* __restrict__ lv,
    short* __restrict__ xr, short* __restrict__ xk, short* __restrict__ xv) {
  const int i = blockIdx.x * 256 + threadIdx.x;
  const int c4 = i % (C_ / 4);
  const int gm = i / (C_ / 4);
  const float4 xa = ((const float4*)x)[i];
  float4 xp = make_float4(0.f, 0.f, 0.f, 0.f);
  if ((gm % T_) != 0) xp = ((const float4*)x)[i - C_ / 4];
  const float4 dx = make_float4(xp.x - xa.x, xp.y - xa.y, xp.z - xa.z, xp.w - xa.w);

  const float4 l1 = ((const float4*)lr)[c4];
  const float4 l2 = ((const float4*)lk)[c4];
  const float4 l3 = ((const float4*)lv)[c4];
  short4 o1 = {bf16b(fmaf(dx.x, l1.x, xa.x)), bf16b(fmaf(dx.y, l1.y, xa.y)),
               bf16b(fmaf(dx.z, l1.z, xa.z)), bf16b(fmaf(dx.w, l1.w, xa.w))};
  short4 o2 = {bf16b(fmaf(dx.x, l2.x, xa.x)), bf16b(fmaf(dx.y, l2.y, xa.y)),
               bf16b(fmaf(dx.z, l2.z, xa.z)), bf16b(fmaf(dx.w, l2.w, xa.w))};
  short4 o3 = {bf16b(fmaf(dx.x, l3.x, xa.x)), bf16b(fmaf(dx.y, l3.y, xa.y)),
               bf16b(fmaf(dx.z, l3.z, xa.z)), bf16b(fmaf(dx.w, l3.w, xa.w))};
  ((short4*)xr)[i] = o1;
  ((short4*)xk)[i] = o2;
  ((short4*)xv)[i] = o3;
}

// ---------------- fp32 -> bf16 convert ----------------
__global__ __launch_bounds__(256) void cvtw_k(const float* __restrict__ in,
                                              short* __restrict__ out, int n4) {
  const int i = blockIdx.x * 256 + threadIdx.x;
  if (i >= n4) return;
  const float4 v = ((const float4*)in)[i];
  short4 o = {bf16b(v.x), bf16b(v.y), bf16b(v.z), bf16b(v.w)};
  ((short4*)out)[i] = o;
}

// ---------------- prep + pack: z,b,k,v slots ----------------
__global__ __launch_bounds__(256) void prep_pack_k(
    const float* __restrict__ k0, const float* __restrict__ a,
    const float* __restrict__ v, const float* __restrict__ k_k,
    const float* __restrict__ k_a, float* __restrict__ pk) {
  const int wid = threadIdx.x >> 6;
  const int lane = threadIdx.x & 63;
  const size_t hid = (size_t)blockIdx.x * 4 + wid;
  const int b = (int)(hid / ((size_t)T_ * H_));
  const int t = (int)((hid / H_) % T_);
  const int h = (int)(hid % H_);
  const size_t idx = hid * 64 + lane;
  const int c = h * 64 + lane;

  const float kv = k0[idx];
  const float av = a[idx];
  const float kk = kv * k_k[c];
  const float ss = wave_sum64(kk * kk);
  const float denom = fmaxf(sqrtf(ss), 1e-12f);
  const float kkn = kk / denom;

  const size_t rec = ((size_t)b * H_ + h) * T_ + t;
  float* pr = pk + rec * REC_;
  pr[64 + lane] = -kkn;
  pr[128 + lane] = kkn * av;
  short* ps = (short*)pr;
  ps[384 + lane] = bf16b(kv * (1.f + (av - 1.f) * k_a[c]));
  ps[512 + lane] = bf16b(v[idx]);
}

// ---------------- WKV-7: LDS-ring pipelined, store-free loop ----------------
// 384 blocks (bh*8 rowgroups) x 64 threads. Wave = 8 rows x 8-lane teams,
// lane holds 8 cols. y buffered in LDS (lgkm domain), flushed every 128 steps
// so the vmcnt(15) gate only ever waits on 3-quad-old prefetch loads.
__global__ __launch_bounds__(64) void wkv7_k(const float* __restrict__ pk,
                                             float* __restrict__ yy) {
  const int bh = blockIdx.x >> 3, rg = blockIdx.x & 7;
  const int lane = threadIdx.x;
  const int l8 = lane & 7, team = lane >> 3;
  const int cb = l8 * 8;
  const int row = rg * 8 + team;
  const float* pkb = pk + (size_t)bh * T_ * REC_ + lane * 4;
  __shared__ float ring[4 * 4 * REC_];   // 20 KB
  __shared__ float ybuf[128 * 8];        // 4 KB

#pragma unroll
  for (int q = 0; q < 3; q++) {
    const float* g = pkb + (size_t)q * (4 * REC_);
    float* l = &ring[(q & 3) * (4 * REC_)];
#pragma unroll
    for (int i = 0; i < 5; i++) GLD16(g + i * 256, l + i * 256);
  }

  float S[8];
#pragma unroll
  for (int c = 0; c < 8; c++) S[c] = 0.f;
  const int b = bh / H_, h = bh % H_;
  float* yb = yy + ((size_t)b * T_) * C_ + h * 64 + rg * 8;

  const int NQ = T_ / 4;
  for (int q = 0; q < NQ; q++) {
    if (q + 3 < NQ) {
      const float* g = pkb + (size_t)(q + 3) * (4 * REC_);
      float* l = &ring[((q + 3) & 3) * (4 * REC_)];
#pragma unroll
      for (int i = 0; i < 5; i++) GLD16(g + i * 256, l + i * 256);
      asm volatile("s_waitcnt vmcnt(15)" ::: "memory");
    } else {
      asm volatile("s_waitcnt vmcnt(0)" ::: "memory");
    }
    const float* rb = &ring[(q & 3) * (4 * REC_)];
#pragma unroll
    for (int d = 0; d < 4; d++) {
      const float* rec = rb + d * REC_;
      float w8[8], z8[8], b8[8], k8[8], r8[8];
      *(float4*)&w8[0] = *(const float4*)(rec + cb);
      *(float4*)&w8[4] = *(const float4*)(rec + cb + 4);
      *(float4*)&z8[0] = *(const float4*)(rec + 64 + cb);
      *(float4*)&z8[4] = *(const float4*)(rec + 64 + cb + 4);
      *(float4*)&b8[0] = *(const float4*)(rec + 128 + cb);
      *(float4*)&b8[4] = *(const float4*)(rec + 128 + cb + 4);
      const ushort* rs = (const ushort*)rec;
      const ushort4 ka = *(const ushort4*)(rs + 384 + cb);
      const ushort4 kb2 = *(const ushort4*)(rs + 384 + cb + 4);
      const ushort4 ra = *(const ushort4*)(rs + 448 + cb);
      const ushort4 rb2 = *(const ushort4*)(rs + 448 + cb + 4);
      k8[0] = ubf(ka.x); k8[1] = ubf(ka.y); k8[2] = ubf(ka.z); k8[3] = ubf(ka.w);
      k8[4] = ubf(kb2.x); k8[5] = ubf(kb2.y); k8[6] = ubf(kb2.z); k8[7] = ubf(kb2.w);
      r8[0] = ubf(ra.x); r8[1] = ubf(ra.y); r8[2] = ubf(ra.z); r8[3] = ubf(ra.w);
      r8[4] = ubf(rb2.x); r8[5] = ubf(rb2.y); r8[6] = ubf(rb2.z); r8[7] = ubf(rb2.w);
      const float vi = ubf(rs[512 + row]);

      float sa = 0.f;
#pragma unroll
      for (int c = 0; c < 8; c++) sa = fmaf(S[c], z8[c], sa);
      sa += __shfl_xor(sa, 1);
      sa += __shfl_xor(sa, 2);
      sa += __shfl_xor(sa, 4);

      float yp = 0.f;
#pragma unroll
      for (int c = 0; c < 8; c++) {
        S[c] = fmaf(S[c], w8[c], fmaf(sa, b8[c], vi * k8[c]));
        yp = fmaf(S[c], r8[c], yp);
      }
      yp += __shfl_xor(yp, 1);
      yp += __shfl_xor(yp, 2);
      yp += __shfl_xor(yp, 4);
      if (l8 == 0) ybuf[((q & 31) * 4 + d) * 8 + team] = yp;
    }
    if ((q & 31) == 31) {
      const int tq = (q - 31) * 4;
#pragma unroll
      for (int i = 0; i < 16; i++) {
        const int e = i * 64 + lane;
        const int sl = e >> 3, r8i = e & 7;
        yb[(size_t)(tq + sl) * C_ + r8i] = ybuf[e];
      }
    }
  }
}

// ---------------- GroupNorm + r_k term + g gating -> bf16 ----------------
__global__ __launch_bounds__(256) void gn_k(
    const float* __restrict__ y, const float* __restrict__ pk,
    const float* __restrict__ v, const float* __restrict__ g,
    const float* __restrict__ r_k, const float* __restrict__ ln_w,
    const float* __restrict__ ln_b, short* __restrict__ ymb) {
  const int wid = threadIdx.x >> 6;
  const int lane = threadIdx.x & 63;
  const size_t hid = (size_t)blockIdx.x * 4 + wid;
  const int b = (int)(hid / ((size_t)T_ * H_));
  const int t = (int)((hid / H_) % T_);
  const int h = (int)(hid % H_);
  const size_t idx = hid * 64 + lane;
  const int c = h * 64 + lane;

  const float yv = y[idx];
  const float mu = wave_sum64(yv) * (1.f / 64.f);
  const float sq = wave_sum64(yv * yv) * (1.f / 64.f);
  const float var = sq - mu * mu;
  float yn = (yv - mu) * rsqrtf(var + 0.00064f);
  yn = yn * ln_w[c] + ln_b[c];

  const size_t rec = ((size_t)b * H_ + h) * T_ + t;
  const short* ps = (const short*)(pk + rec * REC_);
  const float kf = ubf(((const ushort*)ps)[384 + lane]);
  const float rf = ubf(((const ushort*)ps)[448 + lane]);
  const float s = wave_sum64(rf * kf * r_k[c]);
  yn += s * v[idx];
  ymb[idx] = bf16b(yn * g[idx]);
}

// ---------------- copy ----------------
__global__ __launch_bounds__(256) void copy4_k(const float4* __restrict__ src,
                                               float4* __restrict__ dst, int n4) {
  const int i = blockIdx.x * blockDim.x + threadIdx.x;
  if (i < n4) dst[i] = src[i];
}

extern "C" void kernel_launch(void* const* d_in, const int* in_sizes, int n_in,
                              void* d_out, int out_size, void* d_ws,
                              size_t ws_size, hipStream_t stream) {
  const float* x       = (const float*)d_in[0];
  const float* v_first = (const float*)d_in[1];
  const float* lam_r   = (const float*)d_in[2];
  const float* lam_w   = (const float*)d_in[3];
  const float* lam_k   = (const float*)d_in[4];
  const float* lam_v   = (const float*)d_in[5];
  const float* lam_a   = (const float*)d_in[6];
  const float* lam_g   = (const float*)d_in[7];
  const float* w_miu   = (const float*)d_in[8];
  const float* w_A     = (const float*)d_in[9];
  const float* w_B     = (const float*)d_in[10];
  const float* a_miu   = (const float*)d_in[11];
  const float* a_A     = (const float*)d_in[12];
  const float* a_B     = (const float*)d_in[13];
  const float* v_miu   = (const float*)d_in[14];
  const float* v_A     = (const float*)d_in[15];
  const float* v_B     = (const float*)d_in[16];
  const float* g_A     = (const float*)d_in[17];
  const float* g_B     = (const float*)d_in[18];
  const float* k_k     = (const float*)d_in[19];
  const float* k_a     = (const float*)d_in[20];
  const float* r_k     = (const float*)d_in[21];
  const float* W_r     = (const float*)d_in[22];
  const float* W_k     = (const float*)d_in[23];
  const float* W_v     = (const float*)d_in[24];
  const float* W_o     = (const float*)d_in[25];
  const float* ln_w    = (const float*)d_in[26];
  const float* ln_b    = (const float*)d_in[27];

  const int M = M_;                 // 8192
  const size_t S = (size_t)M * C_;  // 6291456
  const int WN = C_ * C_;           // 589824

  float* ws   = (float*)d_ws;
  float* kbuf = ws;                                   // k0; ymb later
  float* vbuf = ws + S;
  float* a_   = ws + 2 * S;                           // a; then y
  float* g_   = ws + 3 * S;
  float* h_   = ws + 4 * S;                           // M*320 floats
  short* wb   = (short*)(h_ + (size_t)M * 320);       // 4*WN shorts
  short* xr   = wb + 4 * (size_t)WN;                  // S shorts
  float* pk   = (float*)(xr + S);                     // 48*2048*320 floats
  short* xk   = (short*)pk;                           // overlay (transient)
  short* xv   = (short*)pk + S;                       // overlay (transient)
  short* ymb  = (short*)kbuf;
  float* out  = (float*)d_out;

  float* h_w = h_;
  float* h_a = h_ + (size_t)M * 64;
  float* h_v = h_ + (size_t)M * 128;
  float* h_g = h_ + (size_t)M * 192;

  short* wrb = wb + 0 * (size_t)WN;
  short* wkb = wb + 1 * (size_t)WN;
  short* wvb = wb + 2 * (size_t)WN;
  short* wob = wb + 3 * (size_t)WN;

  // 1) weights -> bf16
  {
    dim3 blk(256), grid(WN / 4 / 256);
    hipLaunchKernelGGL(cvtw_k, grid, blk, 0, stream, W_r, wrb, WN / 4);
    hipLaunchKernelGGL(cvtw_k, grid, blk, 0, stream, W_k, wkb, WN / 4);
    hipLaunchKernelGGL(cvtw_k, grid, blk, 0, stream, W_v, wvb, WN / 4);
    hipLaunchKernelGGL(cvtw_k, grid, blk, 0, stream, W_o, wob, WN / 4);
  }
  // 2) mixed x -> bf16
  {
    dim3 blk(256), grid((int)(S / 4 / 256));
    hipLaunchKernelGGL(mix3_k, grid, blk, 0, stream, x, lam_r, lam_k, lam_v,
                       xr, xk, xv);
  }
  // 3) k,v projections (consume xk/xv overlays)
  {
    dim3 blk(256), grid(C_ / 128, M / 128);
    hipLaunchKernelGGL((gemm_bf16_k<false>), grid, blk, 0, stream, xk, wkb, kbuf, M, C_, C_);
    hipLaunchKernelGGL((gemm_bf16_k<false>), grid, blk, 0, stream, xv, wvb, vbuf, M, C_, C_);
  }
  // 4) batched A-pass: w/a/g (mix fused) + v low-rank
  {
    BG4 ap;
    ap.p[0] = {x,    w_A, h_w, lam_w, nullptr, nullptr, nullptr, 64,  C_, 1, EPI_TANH};
    ap.p[1] = {x,    a_A, h_a, lam_a, nullptr, nullptr, nullptr, 64,  C_, 1, EPI_NONE};
    ap.p[2] = {x,    g_A, h_g, lam_g, nullptr, nullptr, nullptr, 128, C_, 1, EPI_SIGMOID};
    ap.p[3] = {vbuf, v_A, h_v, nullptr, nullptr, nullptr, nullptr, 64, C_, 0, EPI_NONE};
    dim3 blk(256), grid(2, M / 64, 4);
    hipLaunchKernelGGL(gemm_small_k, grid, blk, 0, stream, ap);
  }
  // 5) batched B-pass: decay->pk, a, g, vmix
  {
    BG4 bp;
    bp.p[0] = {h_w, w_B, pk,   nullptr, w_miu, nullptr, nullptr, C_, 64,  0, EPI_WDECAY};
    bp.p[1] = {h_a, a_B, a_,   nullptr, a_miu, nullptr, nullptr, C_, 64,  0, EPI_SIGBIAS};
    bp.p[2] = {h_g, g_B, g_,   nullptr, nullptr, nullptr, nullptr, C_, 128, 0, EPI_NONE};
    bp.p[3] = {h_v, v_B, vbuf, nullptr, v_miu, vbuf, v_first, C_, 64,  0, EPI_VMIX};
    dim3 blk(256), grid(C_ / 64, M / 64, 4);
    hipLaunchKernelGGL(gemm_small_k, grid, blk, 0, stream, bp);
  }
  // 6) r projection -> packed r-slot
  {
    dim3 blk(256), grid(C_ / 128, M / 128);
    hipLaunchKernelGGL((gemm_bf16_k<true>), grid, blk, 0, stream, xr, wrb, (float*)pk, M, C_, C_);
  }
  // 7) prep + pack z,b,k,v slots
  {
    dim3 grid((B_ * T_ * H_) / 4), blk(256);
    hipLaunchKernelGGL(prep_pack_k, grid, blk, 0, stream, kbuf, a_, vbuf, k_k,
                       k_a, pk);
  }
  // 8) recurrence -> y (a_ slot)
  {
    dim3 grid(B_ * H_ * 8), blk(64);
    hipLaunchKernelGGL(wkv7_k, grid, blk, 0, stream, pk, a_);
  }
  // 9) groupnorm + rk-term + gate -> ymb (kbuf region)
  {
    dim3 grid((B_ * T_ * H_) / 4), blk(256);
    hipLaunchKernelGGL(gn_k, grid, blk, 0, stream, a_, pk, vbuf, g_, r_k,
                       ln_w, ln_b, ymb);
  }
  // 10) output projection
  {
    dim3 blk(256), grid(C_ / 128, M / 128);
    hipLaunchKernelGGL((gemm_bf16_k<false>), grid, blk, 0, stream, ymb, wob, out, M, C_, C_);
  }
  // 11) v_first passthrough
  {
    const int n4 = (int)(S / 4);
    dim3 grid((n4 + 255) / 256), blk(256);
    hipLaunchKernelGGL(copy4_k, grid, blk, 0, stream, (const float4*)v_first,
                       (float4*)(out + S), n4);
  }
}